// Round 2
// baseline (7665.923 us; speedup 1.0000x reference)
//
#include <hip/hip_runtime.h>
#include <hip/hip_bf16.h>

// MD-LSTM (4-direction 2D LSTM) + fused 1x1 conv. f32 baseline, round 1.
// B=32, C=32, H=W=64, HD=128, IN_DIM=288, Z=5*HD=640, OUT=128.
//
// Wavefront over anti-diagonals s=i+j in SCAN coords (flips applied to x
// reads only; reference does not un-flip before the conv).
// h and c live in 2-diagonal parity buffers (slot = i). The 1x1 conv for
// diagonal s-1 is fused into the launch of diagonal s as extra blocks.

#define HDIM 128
#define ZDIM 640
#define KDIM 288

__device__ __forceinline__ float sigmoidf_(float v) {
    return 1.0f / (1.0f + __expf(-v));
}
__device__ __forceinline__ float tanhf_(float v) {
    return 1.0f - 2.0f / (__expf(2.0f * v) + 1.0f);
}

// ---------------------------------------------------------------------------
// One-time transposes:
//   Wt[d][k][col] = W_lin[d][col][k]  (4 x 288 x 640)
//   Wct[c][o]     = W_conv[o][c]      (512 x 128)
// ---------------------------------------------------------------------------
__global__ void transpose_weights(const float* __restrict__ W_lin,
                                  const float* __restrict__ W_conv,
                                  float* __restrict__ Wt,
                                  float* __restrict__ Wct) {
    int idx = blockIdx.x * 256 + threadIdx.x;
    const int NLIN = 4 * ZDIM * KDIM;  // 737280
    if (idx < NLIN) {
        int d = idx / (ZDIM * KDIM);
        int r = idx % (ZDIM * KDIM);
        int col = r / KDIM;
        int k = r % KDIM;
        Wt[d * (ZDIM * KDIM) + k * ZDIM + col] = W_lin[idx];
    } else {
        int idx2 = idx - NLIN;
        if (idx2 < 128 * 512) {
            int o = idx2 / 512, c = idx2 % 512;
            Wct[c * 128 + o] = W_conv[idx2];
        }
    }
}

// x (32,32,64,64) -> x_t[ij][b][c]  (4096 x 32 x 32), LDS-tiled transpose.
__global__ __launch_bounds__(256) void transpose_x(const float* __restrict__ x,
                                                   float* __restrict__ x_t) {
    __shared__ float tile[64][65];
    int tb = blockIdx.x >> 6;  // bc-tile 0..15   (bc = b*32+c, 1024 total)
    int tj = blockIdx.x & 63;  // ij-tile 0..63
    int t = threadIdx.x;
    for (int f = t; f < 4096; f += 256) {
        int r = f >> 6, cix = f & 63;
        tile[r][cix] = x[(size_t)(tb * 64 + r) * 4096 + tj * 64 + cix];
    }
    __syncthreads();
    for (int f = t; f < 4096; f += 256) {
        int rr = f >> 6, cc = f & 63;
        x_t[(size_t)(tj * 64 + rr) * 1024 + tb * 64 + cc] = tile[cc][rr];
    }
}

__global__ void fill_sentinel(float* __restrict__ out) {
    out[blockIdx.x * 256 + threadIdx.x] = 1.0e6f;
}

// ---------------------------------------------------------------------------
// Fused diagonal kernel.
//  blocks [0, nstep): LSTM cells of diagonal s.
//    decode blk = ((d*nc + ci)*4 + bt)*2 + hf
//    thread: lane owns z-column cb = hf*64+lane; warp owns batches
//    {bt*8 + 2w, bt*8 + 2w + 1}; 5 gates x 2 batches = 10 accs, K=288.
//  blocks [nstep, nstep+4*ncp): 1x1 conv for cells of diagonal s-1.
//    decode cb2 = cip*4 + btc; thread: o = t&127, 4 batches.
// ---------------------------------------------------------------------------
__global__ __launch_bounds__(256) void fused_step(
    const float* __restrict__ x_t,    // (4096,32,32) scan-major
    const float* __restrict__ Wt,     // (4,288,640)
    const float* __restrict__ b_lin,  // (4,640)
    const float* __restrict__ Wci, const float* __restrict__ Wf1,
    const float* __restrict__ Wf2, const float* __restrict__ Wco,
    const float* __restrict__ Wct,    // (512,128)
    const float* __restrict__ b_conv, // (128)
    float* __restrict__ h_par,        // (2,4,64,32,128)
    float* __restrict__ c_par,        // (2,4,64,32,128)
    float* __restrict__ out,          // (32,128,64,64)
    int s, int i0, int nc, int i0p, int ncp, int nstep) {
    __shared__ __align__(16) float smem[8 * 512];  // 16 KB, role-dependent

    const int t = threadIdx.x;
    const int blk = blockIdx.x;
    const int par = s & 1, parR = par ^ 1;

    if (blk < nstep) {
        // ---------------- LSTM step block ----------------
        int hf = blk & 1;
        int r = blk >> 1;
        int bt = r & 3;
        r >>= 2;
        int ci = r % nc;
        int d = r / nc;
        int i = i0 + ci, j = s - i;
        int fi = (d & 1) ? 63 - i : i;
        int fj = (d & 2) ? 63 - j : j;

        // stage inp[8][288] = concat(x(32), h_up(128), h_left(128))
        {
            int bb = t >> 5, c = t & 31;  // 256 threads -> 8x32 x-part
            smem[bb * KDIM + c] =
                x_t[(size_t)(fi * 64 + fj) * 1024 + (bt * 8 + bb) * 32 + c];
        }
        {
            const float* hu =
                (i > 0) ? h_par + (((size_t)(parR * 4 + d) * 64 + (i - 1)) * 32 +
                                   bt * 8) * HDIM
                        : nullptr;
            const float* hl =
                (j > 0) ? h_par + (((size_t)(parR * 4 + d) * 64 + i) * 32 +
                                   bt * 8) * HDIM
                        : nullptr;
            int bb = t >> 5, k4 = t & 31;  // 256 float4 = 8b x 32k4
            float4 z4 = make_float4(0.f, 0.f, 0.f, 0.f);
            float4 vu = hu ? ((const float4*)hu)[t] : z4;
            float4 vl = hl ? ((const float4*)hl)[t] : z4;
            *(float4*)&smem[bb * KDIM + 32 + k4 * 4] = vu;
            *(float4*)&smem[bb * KDIM + 160 + k4 * 4] = vl;
        }
        __syncthreads();

        const int lane = t & 63, w = t >> 6;
        const int cb = hf * 64 + lane;
        const float* wp = Wt + (size_t)d * (KDIM * ZDIM) + cb;
        const float* xr0 = smem + (w * 2 + 0) * KDIM;
        const float* xr1 = smem + (w * 2 + 1) * KDIM;

        float acc[5][2];
#pragma unroll
        for (int g = 0; g < 5; ++g) {
            float bv = b_lin[d * ZDIM + g * 128 + cb];
            acc[g][0] = bv;
            acc[g][1] = bv;
        }
#pragma unroll 4
        for (int kk = 0; kk < KDIM; ++kk) {
            const float* wr = wp + (size_t)kk * ZDIM;
            float x0 = xr0[kk], x1 = xr1[kk];
#pragma unroll
            for (int g = 0; g < 5; ++g) {
                float wv = wr[g * 128];
                acc[g][0] = fmaf(wv, x0, acc[g][0]);
                acc[g][1] = fmaf(wv, x1, acc[g][1]);
            }
        }

        const float wciv = Wci[d * HDIM + cb];
        const float wf1v = Wf1[d * HDIM + cb];
        const float wf2v = Wf2[d * HDIM + cb];
        const float wcov = Wco[d * HDIM + cb];
        size_t wbase = ((size_t)(par * 4 + d) * 64 + i) * 32 * HDIM;
        float* cw = c_par + wbase;
        float* hw = h_par + wbase;
        const float* cu_b =
            (i > 0) ? c_par + ((size_t)(parR * 4 + d) * 64 + (i - 1)) * 32 * HDIM
                    : nullptr;
        const float* cl_b =
            (j > 0) ? c_par + ((size_t)(parR * 4 + d) * 64 + i) * 32 * HDIM
                    : nullptr;
#pragma unroll
        for (int p = 0; p < 2; ++p) {
            int b = bt * 8 + w * 2 + p;
            float cu = cu_b ? cu_b[b * HDIM + cb] : 0.f;
            float cl = cl_b ? cl_b[b * HDIM + cb] : 0.f;
            float ig = sigmoidf_(acc[0][p] + wciv * (cu + cl));
            float f1 = sigmoidf_(acc[1][p] + wf1v * cu);
            float f2 = sigmoidf_(acc[2][p] + wf2v * cl);
            float cn = f1 * cu + f2 * cl + ig * tanhf_(acc[3][p]);
            float oo = sigmoidf_(acc[4][p] + wcov * cn);
            float hn = oo * tanhf_(cn);
            cw[b * HDIM + cb] = cn;
            hw[b * HDIM + cb] = hn;
        }
    } else {
        // ---------------- fused conv block (diagonal s-1) ----------------
        int cb2 = blk - nstep;
        int btc = cb2 & 3, cip = cb2 >> 2;
        int ip = i0p + cip, jp = (s - 1) - ip;

        // stage hs[8 b][512 c]: c = d*128 + k, from read-parity buffer
        for (int f = t; f < 1024; f += 256) {  // 1024 float4
            int d = f >> 8, rem = f & 255;
            int bb = rem >> 5, k4 = rem & 31;
            const float4* src =
                (const float4*)(h_par + (((size_t)(parR * 4 + d) * 64 + ip) * 32 +
                                         btc * 8 + bb) * HDIM);
            *(float4*)&smem[bb * 512 + d * 128 + k4 * 4] = src[k4];
        }
        __syncthreads();

        const int o = t & 127, half = t >> 7;
        float acc[4];
#pragma unroll
        for (int q = 0; q < 4; ++q) acc[q] = b_conv[o];
#pragma unroll 4
        for (int c = 0; c < 512; ++c) {
            float wv = Wct[c * 128 + o];
#pragma unroll
            for (int q = 0; q < 4; ++q)
                acc[q] = fmaf(smem[(half * 4 + q) * 512 + c], wv, acc[q]);
        }
#pragma unroll
        for (int q = 0; q < 4; ++q) {
            int b = btc * 8 + half * 4 + q;
            out[(size_t)(b * 128 + o) * 4096 + ip * 64 + jp] = acc[q];
        }
    }
}

// ---------------------------------------------------------------------------
extern "C" void kernel_launch(void* const* d_in, const int* in_sizes, int n_in,
                              void* d_out, int out_size, void* d_ws,
                              size_t ws_size, hipStream_t stream) {
    const float* x = (const float*)d_in[0];
    const float* W_lin = (const float*)d_in[1];
    const float* b_lin = (const float*)d_in[2];
    const float* Wci = (const float*)d_in[3];
    const float* Wf1 = (const float*)d_in[4];
    const float* Wf2 = (const float*)d_in[5];
    const float* Wco = (const float*)d_in[6];
    const float* W_conv = (const float*)d_in[7];
    const float* b_conv = (const float*)d_in[8];
    float* out = (float*)d_out;

    // workspace (floats)
    const size_t N_HPAR = 2ull * 4 * 64 * 32 * 128;  // 2,097,152
    const size_t N_WT = 4ull * KDIM * ZDIM;          //   737,280
    const size_t N_WCT = 512ull * 128;               //    65,536
    const size_t N_XT = 4096ull * 1024;              // 4,194,304
    float* h_par = (float*)d_ws;
    float* c_par = h_par + N_HPAR;
    float* Wt = c_par + N_HPAR;
    float* Wct = Wt + N_WT;
    float* x_t = Wct + N_WCT;
    size_t need = (2 * N_HPAR + N_WT + N_WCT + N_XT) * 4ull;
    if (ws_size < need) {  // visible failure signature: out = 1e6
        fill_sentinel<<<(out_size + 255) / 256, 256, 0, stream>>>(out);
        return;
    }

    transpose_weights<<<3136, 256, 0, stream>>>(W_lin, W_conv, Wt, Wct);
    transpose_x<<<1024, 256, 0, stream>>>(x, x_t);

    for (int s = 0; s <= 127; ++s) {
        int i0 = 0, nc = 0;
        if (s <= 126) {
            i0 = s > 63 ? s - 63 : 0;
            int i1 = s < 63 ? s : 63;
            nc = i1 - i0 + 1;
        }
        int i0p = 0, ncp = 0;
        if (s >= 1) {
            int sp = s - 1;
            i0p = sp > 63 ? sp - 63 : 0;
            int i1p = sp < 63 ? sp : 63;
            ncp = i1p - i0p + 1;
        }
        int nstep = 32 * nc;
        int nconv = 4 * ncp;
        fused_step<<<nstep + nconv, 256, 0, stream>>>(
            x_t, Wt, b_lin, Wci, Wf1, Wf2, Wco, Wct, b_conv, h_par, c_par, out,
            s, i0, nc, i0p, ncp, nstep);
    }
}